// Round 19
// baseline (208.343 us; speedup 1.0000x reference)
//
#include <hip/hip_runtime.h>
#include <hip/hip_bf16.h>
#include <cstdint>

#define NB 4
#define TT 2048
#define DM 1024
#define NH 16
#define HD 64
#define QBLK 256
#define KVB 128

typedef __attribute__((ext_vector_type(8))) short bf16x8;
typedef __attribute__((ext_vector_type(4))) float f32x4;
typedef __attribute__((ext_vector_type(16))) float f32x16;
typedef __attribute__((ext_vector_type(4))) float float4v;
typedef __attribute__((ext_vector_type(4))) int i32x4;

static __device__ __forceinline__ unsigned short f2bf(float x) {
    unsigned int u = __float_as_uint(x);
    unsigned int r = (u + 0x7fffu + ((u >> 16) & 1u)) >> 16;
    return (unsigned short)r;
}
// packed f32 pair -> bf16x2 (compiler emits v_cvt_pk_bf16_f32)
static __device__ __forceinline__ uint32_t pk2bf(float lo, float hi) {
    union { __hip_bfloat162 v; uint32_t u; } c;
    c.v = __float22bfloat162_rn(float2{lo, hi});
    return c.u;
}

#define GLOAD16(gp, lp) __builtin_amdgcn_global_load_lds(                 \
    (const __attribute__((address_space(1))) void*)(gp),                  \
    (__attribute__((address_space(3))) void*)(lp), 16, 0, 0)
#define BAR() asm volatile("s_barrier" ::: "memory")
#define WAITV8() asm volatile("s_waitcnt vmcnt(8)" ::: "memory")
#define WAITV4() asm volatile("s_waitcnt vmcnt(4)" ::: "memory")
#define WAITV2() asm volatile("s_waitcnt vmcnt(2)" ::: "memory")
#define WAITV0() asm volatile("s_waitcnt vmcnt(0)" ::: "memory")

// ---- prep: z<4 -> transpose weight z (f32->bf16, Wt[n][k]);
//            z in 4..6 -> bulk f32->bf16 convert of xq/xk/xv ----
__global__ __launch_bounds__(256) void k_prep(const float* __restrict__ W0,
                                              const float* __restrict__ W1,
                                              const float* __restrict__ W2,
                                              const float* __restrict__ W3,
                                              unsigned short* __restrict__ Wt,
                                              const float* __restrict__ sq,
                                              const float* __restrict__ sk,
                                              const float* __restrict__ sv,
                                              unsigned short* __restrict__ Xb,
                                              int n8) {
    const int z = blockIdx.z;
    const int tx = threadIdx.x, ty = threadIdx.y;
    if (z < 4) {
        __shared__ unsigned short tile[32][33];
        const float* W = (z == 0) ? W0 : (z == 1) ? W1 : (z == 2) ? W2 : W3;
        unsigned short* dst = Wt + (size_t)z * DM * DM;
        int kb = blockIdx.x * 32, nb = blockIdx.y * 32;
#pragma unroll
        for (int i = 0; i < 4; ++i)
            tile[ty + i * 8][tx] = f2bf(W[(size_t)(kb + ty + i * 8) * DM + nb + tx]);
        __syncthreads();
#pragma unroll
        for (int i = 0; i < 4; ++i)
            dst[(size_t)(nb + ty + i * 8) * DM + kb + tx] = tile[tx][ty + i * 8];
    } else {
        const int c = z - 4;
        const float* s = (c == 0) ? sq : (c == 1) ? sk : sv;
        unsigned short* d = Xb + (size_t)c * n8 * 8;
        const int tid = ty * 32 + tx;
        int i = (blockIdx.y * 32 + blockIdx.x) * 256 + tid;
        const int stride = 32 * 32 * 256;
        for (; i < n8; i += stride) {
            const float4v* sp = (const float4v*)(s + (size_t)i * 8);
            float4v v0 = sp[0], v1 = sp[1];
            uint4 o;
            o.x = pk2bf(v0[0], v0[1]);
            o.y = pk2bf(v0[2], v0[3]);
            o.z = pk2bf(v1[0], v1[1]);
            o.w = pk2bf(v1[2], v1[3]);
            *(uint4*)(d + (size_t)i * 8) = o;
        }
    }
}

// ---- QKV GEMM, 256x256 tile, 8 waves, phase-split schedule ----
// BK=64, double-buffered 2x(32KB A + 32KB B) LDS, XOR swizzle (row&7)<<4.
// Loads span barriers: tile t+1's 8 gload_lds issue at phase 0, vmcnt(8)
// (never a mid-loop drain). 4 phases/K-tile: {ds_read A-quad -> 16 MFMA ->
// barrier}, B-frags read once in phase 0 and held in registers.
// grid.z in {0,1,2}: z<2 scatter bf16 [b,h,t,d]; z==2 writes V^T [bh][d][t].
__global__ __launch_bounds__(512) void k_gemm8(const unsigned short* __restrict__ A0,
                                               const unsigned short* __restrict__ Bt0,
                                               const float* __restrict__ bq,
                                               const float* __restrict__ bk,
                                               const float* __restrict__ bv,
                                               unsigned short* __restrict__ QKb,
                                               unsigned short* __restrict__ Vt,
                                               float qscale) {
    __shared__ __align__(16) char Asl[2][32768];
    __shared__ __align__(16) char Bsl[2][32768];
    const int tid = threadIdx.x;
    const int lane = tid & 63, wid = tid >> 6;
    const int lg = lane >> 4, lc = lane & 15;
    const int wr = wid >> 2, wc = wid & 3;  // 2M x 4N waves, 128x64 out each
    const int m0 = blockIdx.x * 256, n0 = blockIdx.y * 256;
    const int z = blockIdx.z;

    const char* Ab = (const char*)(A0 + (size_t)z * NB * TT * DM);
    const char* Bb = (const char*)(Bt0 + (size_t)z * DM * DM);
    const float* bias = (z == 0) ? bq : (z == 1) ? bk : bv;
    const float scale = (z == 0) ? qscale : 1.0f;

    f32x4 acc[8][4];
#pragma unroll
    for (int mi = 0; mi < 8; ++mi)
#pragma unroll
        for (int ni = 0; ni < 4; ++ni)
            acc[mi][ni] = (f32x4){0.f, 0.f, 0.f, 0.f};

    const int srow = tid >> 3;        // 0..63
    const int scol = (tid & 7) * 16;  // byte within 128B row
    auto stage = [&](int buf, int k0) {
#pragma unroll
        for (int j = 0; j < 4; ++j) {
            const int row = j * 64 + srow;
            const int swz = scol ^ ((row & 7) << 4);
            GLOAD16(Ab + (size_t)(m0 + row) * (DM * 2) + k0 * 2 + swz,
                    &Asl[buf][0] + j * 8192 + tid * 16);
        }
#pragma unroll
        for (int j = 0; j < 4; ++j) {
            const int row = j * 64 + srow;
            const int swz = scol ^ ((row & 7) << 4);
            GLOAD16(Bb + (size_t)(n0 + row) * (DM * 2) + k0 * 2 + swz,
                    &Bsl[buf][0] + j * 8192 + tid * 16);
        }
    };

    stage(0, 0);  // prologue: tile 0 in flight (published by phase-0 wait)

    int cur = 0;
    for (int t = 0; t < DM / 64; ++t) {
        // ---- phase 0: prefetch next tile, publish current, B-frags + quad 0
        if (t + 1 < DM / 64) {
            stage(cur ^ 1, (t + 1) * 64);  // prev iter's final BAR made cur^1 free
            WAITV8();                      // tile t's 8 done; t+1's 8 in flight
        } else {
            WAITV0();
        }
        BAR();

        bf16x8 bfr[4][2];
#pragma unroll
        for (int ni = 0; ni < 4; ++ni)
#pragma unroll
            for (int kk = 0; kk < 2; ++kk) {
                const int n = wc * 64 + ni * 16 + lc;
                bfr[ni][kk] = *(const bf16x8*)(&Bsl[cur][0] + n * 128 +
                                               ((kk * 64 + lg * 16) ^ ((n & 7) << 4)));
            }

#pragma unroll
        for (int p = 0; p < 4; ++p) {
            bf16x8 af[2][2];
#pragma unroll
            for (int mi2 = 0; mi2 < 2; ++mi2)
#pragma unroll
                for (int kk = 0; kk < 2; ++kk) {
                    const int m = wr * 128 + (p * 2 + mi2) * 16 + lc;
                    af[mi2][kk] = *(const bf16x8*)(&Asl[cur][0] + m * 128 +
                                                   ((kk * 64 + lg * 16) ^ ((m & 7) << 4)));
                }
            __builtin_amdgcn_s_setprio(1);
#pragma unroll
            for (int mi2 = 0; mi2 < 2; ++mi2)
#pragma unroll
                for (int ni = 0; ni < 4; ++ni)
#pragma unroll
                    for (int kk = 0; kk < 2; ++kk)
                        acc[p * 2 + mi2][ni] = __builtin_amdgcn_mfma_f32_16x16x32_bf16(
                            af[mi2][kk], bfr[ni][kk], acc[p * 2 + mi2][ni], 0, 0, 0);
            __builtin_amdgcn_s_setprio(0);
            BAR();  // phase boundary; p=3's BAR also frees cur for next stores
        }
        cur ^= 1;
    }

    // ---- epilogue ----
#pragma unroll
    for (int mi = 0; mi < 8; ++mi)
#pragma unroll
        for (int ni = 0; ni < 4; ++ni) {
            const int m = m0 + wr * 128 + mi * 16 + lg * 4;
            const int n = n0 + wc * 64 + ni * 16 + lc;
            float v[4];
#pragma unroll
            for (int r = 0; r < 4; ++r) v[r] = (acc[mi][ni][r] + bias[n]) * scale;
            const int b = m >> 11, tl = m & (TT - 1), h = n >> 6, d = n & 63;
            if (z == 2) {
                uint2 w;
                w.x = pk2bf(v[0], v[1]);
                w.y = pk2bf(v[2], v[3]);
                *(uint2*)(Vt + ((size_t)(b * NH + h) * HD + d) * TT + tl) = w;
            } else {
#pragma unroll
                for (int r = 0; r < 4; ++r)
                    QKb[(size_t)z * NB * NH * TT * HD +
                        (((size_t)b * NH + h) * TT + tl + r) * HD + d] = f2bf(v[r]);
            }
        }
}

// ---- Wo GEMM: 128x128 tile, m97-style (proven; 512-block grid, 2/CU) ----
__global__ __launch_bounds__(256) void k_gemm_o(const unsigned short* __restrict__ A,
                                                const unsigned short* __restrict__ Bt,
                                                const float* __restrict__ bias,
                                                float* __restrict__ C) {
    __shared__ __align__(16) char Asl[2][16384];
    __shared__ __align__(16) char Bsl[2][16384];
    const int tid = threadIdx.x;
    const int lane = tid & 63, wid = tid >> 6;
    const int lg = lane >> 4, lc = lane & 15;
    const int wm = wid >> 1, wn = wid & 1;
    const int m0 = blockIdx.x * 128, n0 = blockIdx.y * 128;

    const char* Ab = (const char*)A;
    const char* Bb = (const char*)Bt;

    f32x4 acc[4][4];
#pragma unroll
    for (int mi = 0; mi < 4; ++mi)
#pragma unroll
        for (int ni = 0; ni < 4; ++ni)
            acc[mi][ni] = (f32x4){0.f, 0.f, 0.f, 0.f};

    auto stage = [&](int buf, int k0) {
#pragma unroll
        for (int j = 0; j < 4; ++j) {
            const int row = j * 32 + (tid >> 3);
            const int swz = ((tid & 7) * 16) ^ ((row & 7) << 4);
            GLOAD16(Ab + (size_t)(m0 + row) * (DM * 2) + k0 * 2 + swz,
                    &Asl[buf][0] + j * 4096 + tid * 16);
            GLOAD16(Bb + (size_t)(n0 + row) * (DM * 2) + k0 * 2 + swz,
                    &Bsl[buf][0] + j * 4096 + tid * 16);
        }
    };

    stage(0, 0);
    __syncthreads();

    int cur = 0;
    for (int t = 0; t < DM / 64; ++t) {
        if (t + 1 < DM / 64) {
            stage(cur ^ 1, (t + 1) * 64);
            WAITV8();
        } else {
            WAITV0();
        }
        BAR();

#pragma unroll
        for (int kk = 0; kk < 2; ++kk) {
            bf16x8 af[4], bfr[4];
#pragma unroll
            for (int ni = 0; ni < 4; ++ni) {
                const int n = wn * 64 + ni * 16 + lc;
                bfr[ni] = *(const bf16x8*)(&Bsl[cur][0] + n * 128 +
                                           ((kk * 64 + lg * 16) ^ ((n & 7) << 4)));
            }
#pragma unroll
            for (int mi = 0; mi < 4; ++mi) {
                const int m = wm * 64 + mi * 16 + lc;
                af[mi] = *(const bf16x8*)(&Asl[cur][0] + m * 128 +
                                          ((kk * 64 + lg * 16) ^ ((m & 7) << 4)));
            }
            __builtin_amdgcn_s_setprio(1);
#pragma unroll
            for (int mi = 0; mi < 4; ++mi)
#pragma unroll
                for (int ni = 0; ni < 4; ++ni)
                    acc[mi][ni] = __builtin_amdgcn_mfma_f32_16x16x32_bf16(af[mi], bfr[ni],
                                                                          acc[mi][ni], 0, 0, 0);
            __builtin_amdgcn_s_setprio(0);
        }
        BAR();
        cur ^= 1;
    }

#pragma unroll
    for (int mi = 0; mi < 4; ++mi)
#pragma unroll
        for (int ni = 0; ni < 4; ++ni)
#pragma unroll
            for (int r = 0; r < 4; ++r) {
                int m = m0 + wm * 64 + mi * 16 + lg * 4 + r;
                int n = n0 + wn * 64 + ni * 16 + lc;
                C[(size_t)m * DM + n] = acc[mi][ni][r] + bias[n];
            }
}

// ---- flash attention (round-16/18 measured-best form, unchanged) ----
__global__ __launch_bounds__(512) void k_attn(const unsigned short* __restrict__ Qg,
                                              const unsigned short* __restrict__ Kg,
                                              const unsigned short* __restrict__ Vtg,
                                              const int* __restrict__ pm,
                                              unsigned short* __restrict__ Og) {
    __shared__ __align__(16) unsigned short Kl[2][KVB * HD];
    __shared__ __align__(16) unsigned short Vl[2][KVB * HD];
    __shared__ uint64_t pmbits[TT / 64];

    const int idx = blockIdx.x;
    const int half = idx >> 8, r5 = idx & 255;
    const int a = r5 & 3;
    const int qb = half ? (7 - a) : a;
    const int bh = r5 >> 2;
    const int b = bh >> 4, h = bh & 15;
    const int qbase = qb * QBLK;
    const int tid = threadIdx.x;
    const int wid = tid >> 6, lane = tid & 63;
    const int hi = lane >> 5, l31 = lane & 31;
    const int q0 = qbase + wid * 32;
    const int q = q0 + l31;

    const unsigned short* Qh = Qg + (size_t)bh * TT * HD;
    const char* Khb = (const char*)(Kg + (size_t)bh * TT * HD);
    const char* Vthb = (const char*)(Vtg + (size_t)bh * HD * TT);
    const int* pmb = pm + b * TT;

    char* const kdst = (char*)&Kl[0][0];
    char* const vdst = (char*)&Vl[0][0];

#define ASTAGE(buf, kv0_)                                                        \
    {                                                                            \
        _Pragma("unroll")                                                        \
        for (int p = 0; p < 2; ++p) {                                            \
            GLOAD16(Khb + (size_t)((kv0_) + p * 64 + lane) * 128 + wid * 16,     \
                    kdst + (buf) * 16384 + wid * 2048 + p * 1024 + lane * 16);   \
            GLOAD16(Vthb + (size_t)lane * 4096 + (size_t)(kv0_) * 2 + (p * 8 + wid) * 16, \
                    vdst + (buf) * 16384 + p * 8192 + wid * 1024 + lane * 16);   \
        }                                                                        \
    }

    ASTAGE(0, 0);

#pragma unroll
    for (int it = 0; it < 4; ++it) {
        const int g = wid + it * 8;
        unsigned long long msk = __ballot(pmb[g * 64 + lane] != 0);
        if (lane == 0) pmbits[g] = msk;
    }

    bf16x8 qf[4];
#pragma unroll
    for (int dd = 0; dd < 4; ++dd)
        qf[dd] = *(const bf16x8*)((const char*)Qh + (size_t)q * 128 + dd * 32 + hi * 16);

    f32x16 o0, o1;
#pragma unroll
    for (int r = 0; r < 16; ++r) { o0[r] = 0.f; o1[r] = 0.f; }
    float mrow = -INFINITY, msafe = -1.0e30f, lrow = 0.f;

    __syncthreads();

    const int nt = (qbase + QBLK) >> 7;
    int cur = 0;
    for (int t = 0; t < nt; ++t) {
        const int kv0 = t << 7;
        if (t + 1 < nt) {
            ASTAGE(cur ^ 1, kv0 + KVB);
            WAITV4();
        } else {
            WAITV0();
        }
        BAR();

        const char* kb = (const char*)&Kl[0][0] + cur * 16384;
        const char* vbp = (const char*)&Vl[0][0] + cur * 16384;

#pragma unroll
        for (int hh = 0; hh < 2; ++hh) {
            const int k0 = kv0 + hh * 64;
            if (k0 > q0 + 31) continue;

            const uint64_t vb = pmbits[k0 >> 6];
            const uint32_t pm0 = ((uint32_t)vb) >> (4 * hi);
            const uint32_t pm1 = ((uint32_t)(vb >> 32)) >> (4 * hi);
            const bool allvalid = (vb == ~0ull);
            const bool do2 = (k0 + 32 <= q0 + 31);
            const bool needmask = (k0 + 63 > q0) || !allvalid;
            const char* kbh = kb + hh * 1024;
            const char* vbh = vbp + hh * 8192;

            f32x16 st0, st1;
#pragma unroll
            for (int r = 0; r < 16; ++r) { st0[r] = 0.f; st1[r] = 0.f; }
            __builtin_amdgcn_s_setprio(1);
#pragma unroll
            for (int dd = 0; dd < 4; ++dd) {
                const char* kchunk = kbh + (dd * 2 + hi) * 2048;
                bf16x8 kf = *(const bf16x8*)(kchunk + l31 * 16);
                st0 = __builtin_amdgcn_mfma_f32_32x32x16_bf16(kf, qf[dd], st0, 0, 0, 0);
            }
            if (do2) {
#pragma unroll
                for (int dd = 0; dd < 4; ++dd) {
                    const char* kchunk = kbh + (dd * 2 + hi) * 2048;
                    bf16x8 kf = *(const bf16x8*)(kchunk + 512 + l31 * 16);
                    st1 = __builtin_amdgcn_mfma_f32_32x32x16_bf16(kf, qf[dd], st1, 0, 0, 0);
                }
            }
            __builtin_amdgcn_s_setprio(0);

            const int qr = q - k0 - 4 * hi;
            if (needmask) {
#pragma unroll
                for (int r = 0; r < 16; ++r) {
                    const int c = (r & 3) + 8 * (r >> 2);
                    st0[r] = (((pm0 >> c) & 1) && (c <= qr)) ? st0[r] : -INFINITY;
                }
                if (do2) {
#pragma unroll
                    for (int r = 0; r < 16; ++r) {
                        const int c = (r & 3) + 8 * (r >> 2);
                        st1[r] = (((pm1 >> c) & 1) && (c + 32 <= qr)) ? st1[r] : -INFINITY;
                    }
                }
            }

            float mloc = -INFINITY;
#pragma unroll
            for (int r = 0; r < 16; ++r) mloc = fmaxf(mloc, st0[r]);
            if (do2) {
#pragma unroll
                for (int r = 0; r < 16; ++r) mloc = fmaxf(mloc, st1[r]);
            }
            const float cmax = fmaxf(mloc, __shfl_xor(mloc, 32, 64));
            if (!__all(cmax - mrow <= 8.0f)) {
                const float mnew = fmaxf(mrow, cmax);
                const float ms = fmaxf(mnew, -1.0e30f);
                const float esc = __builtin_amdgcn_exp2f(mrow - ms);
#pragma unroll
                for (int r = 0; r < 16; ++r) { o0[r] *= esc; o1[r] *= esc; }
                lrow *= esc;
                mrow = mnew;
                msafe = ms;
            }

            float tot = 0.f;
#pragma unroll
            for (int r = 0; r < 16; ++r) {
                st0[r] = __builtin_amdgcn_exp2f(st0[r] - msafe);
                tot += st0[r];
            }
            if (do2) {
#pragma unroll
                for (int r = 0; r < 16; ++r) {
                    st1[r] = __builtin_amdgcn_exp2f(st1[r] - msafe);
                    tot += st1[r];
                }
            }
            lrow += tot + __shfl_xor(tot, 32, 64);

            __builtin_amdgcn_s_setprio(1);
#pragma unroll
            for (int kc = 0; kc < 2; ++kc) {
                uint32_t A0 = pk2bf(st0[kc * 8 + 0], st0[kc * 8 + 1]);
                uint32_t A1 = pk2bf(st0[kc * 8 + 2], st0[kc * 8 + 3]);
                uint32_t C0 = pk2bf(st0[kc * 8 + 4], st0[kc * 8 + 5]);
                uint32_t C1 = pk2bf(st0[kc * 8 + 6], st0[kc * 8 + 7]);
                uint32_t oA0 = __shfl_xor(A0, 32, 64), oA1 = __shfl_xor(A1, 32, 64);
                uint32_t oC0 = __shfl_xor(C0, 32, 64), oC1 = __shfl_xor(C1, 32, 64);
                i32x4 pf = {(int)(hi ? oC0 : A0), (int)(hi ? oC1 : A1),
                            (int)(hi ? C0 : oA0), (int)(hi ? C1 : oA1)};
                bf16x8 pb = *(bf16x8*)&pf;
                const char* vchunk = vbh + (kc * 2 + hi) * 1024;
                {
                    bf16x8 vf = *(const bf16x8*)(vchunk + l31 * 16);
                    o0 = __builtin_amdgcn_mfma_f32_32x32x16_bf16(vf, pb, o0, 0, 0, 0);
                }
                {
                    bf16x8 vf = *(const bf16x8*)(vchunk + 512 + l31 * 16);
                    o1 = __builtin_amdgcn_mfma_f32_32x32x16_bf16(vf, pb, o1, 0, 0, 0);
                }
            }
            if (do2) {
#pragma unroll
                for (int kc = 0; kc < 2; ++kc) {
                    uint32_t A0 = pk2bf(st1[kc * 8 + 0], st1[kc * 8 + 1]);
                    uint32_t A1 = pk2bf(st1[kc * 8 + 2], st1[kc * 8 + 3]);
                    uint32_t C0 = pk2bf(st1[kc * 8 + 4], st1[kc * 8 + 5]);
                    uint32_t C1 = pk2bf(st1[kc * 8 + 6], st1[kc * 8 + 7]);
                    uint32_t oA0 = __shfl_xor(A0, 32, 64), oA1 = __shfl_xor(A1, 32, 64);
                    uint32_t oC0 = __shfl_xor(C0, 32, 64), oC1 = __shfl_xor(C1, 32, 64);
                    i32x4 pf = {(int)(hi ? oC0 : A0), (int)(hi ? oC1 : A1),
                                (int)(hi ? C0 : oA0), (int)(hi ? C1 : oA1)};
                    bf16x8 pb = *(bf16x8*)&pf;
                    const char* vchunk = vbh + (4 + kc * 2 + hi) * 1024;
                    {
                        bf16x8 vf = *(const bf16x8*)(vchunk + l31 * 16);
                        o0 = __builtin_amdgcn_mfma_f32_32x32x16_bf16(vf, pb, o0, 0, 0, 0);
                    }
                    {
                        bf16x8 vf = *(const bf16x8*)(vchunk + 512 + l31 * 16);
                        o1 = __builtin_amdgcn_mfma_f32_32x32x16_bf16(vf, pb, o1, 0, 0, 0);
                    }
                }
            }
            __builtin_amdgcn_s_setprio(0);
        }
        BAR();
        cur ^= 1;
    }

    const float inv = (lrow > 0.f) ? (1.0f / lrow) : 0.f;
    unsigned short* orow = Og + ((size_t)(b * TT + q)) * DM + h * HD;
#pragma unroll
    for (int g4 = 0; g4 < 4; ++g4) {
        uint32_t w0 = pk2bf(o0[g4 * 4 + 0] * inv, o0[g4 * 4 + 1] * inv);
        uint32_t w1 = pk2bf(o0[g4 * 4 + 2] * inv, o0[g4 * 4 + 3] * inv);
        *(uint2*)(orow + g4 * 8 + 4 * hi) = make_uint2(w0, w1);
    }
#pragma unroll
    for (int g4 = 0; g4 < 4; ++g4) {
        uint32_t w0 = pk2bf(o1[g4 * 4 + 0] * inv, o1[g4 * 4 + 1] * inv);
        uint32_t w1 = pk2bf(o1[g4 * 4 + 2] * inv, o1[g4 * 4 + 3] * inv);
        *(uint2*)(orow + 32 + g4 * 8 + 4 * hi) = make_uint2(w0, w1);
    }
}

extern "C" void kernel_launch(void* const* d_in, const int* in_sizes, int n_in,
                              void* d_out, int out_size, void* d_ws, size_t ws_size,
                              hipStream_t stream) {
    const float* xq = (const float*)d_in[0];
    const float* xk = (const float*)d_in[1];
    const float* xv = (const float*)d_in[2];
    const int* pmask = (const int*)d_in[3];
    const float* Wq = (const float*)d_in[4];
    const float* bq = (const float*)d_in[5];
    const float* Wk = (const float*)d_in[6];
    const float* bk = (const float*)d_in[7];
    const float* Wv = (const float*)d_in[8];
    const float* bv = (const float*)d_in[9];
    const float* Wo = (const float*)d_in[10];
    const float* bo = (const float*)d_in[11];

    char* ws = (char*)d_ws;
    const size_t WT = (size_t)DM * DM * 2;
    const size_t QKV = (size_t)NB * NH * TT * HD * 2;
    unsigned short* WqT = (unsigned short*)(ws + 0 * WT);
    unsigned short* WoT = WqT + 3 * (size_t)DM * DM;
    unsigned short* Qb = (unsigned short*)(ws + 4 * WT);
    unsigned short* Kb = (unsigned short*)(ws + 4 * WT + QKV);
    unsigned short* Vt = (unsigned short*)(ws + 4 * WT + 2 * QKV);
    unsigned short* Ob = (unsigned short*)(ws + 4 * WT + 3 * QKV);
    unsigned short* Xb = (unsigned short*)(ws + 4 * WT + 4 * QKV);

    const float qscale = 0.125f * 1.44269504088896340736f;
    const int n8 = NB * TT * DM / 8;

    k_prep<<<dim3(32, 32, 7), dim3(32, 8), 0, stream>>>(Wq, Wk, Wv, Wo, WqT,
                                                        xq, xk, xv, Xb, n8);
    k_gemm8<<<dim3(32, 4, 3), 512, 0, stream>>>(Xb, WqT, bq, bk, bv, Qb, Vt, qscale);

    k_attn<<<dim3((TT / QBLK) * NB * NH), 512, 0, stream>>>(Qb, Kb, Vt, pmask, Ob);

    k_gemm_o<<<dim3(64, 8), 256, 0, stream>>>(Ob, WoT, bo, (float*)d_out);
}

// Round 20
// 196.674 us; speedup vs baseline: 1.0593x; 1.0593x over previous
//
#include <hip/hip_runtime.h>
#include <hip/hip_bf16.h>
#include <cstdint>

#define NB 4
#define TT 2048
#define DM 1024
#define NH 16
#define HD 64
#define QBLK 256
#define KVB 128

typedef __attribute__((ext_vector_type(8))) short bf16x8;
typedef __attribute__((ext_vector_type(4))) float f32x4;
typedef __attribute__((ext_vector_type(16))) float f32x16;
typedef __attribute__((ext_vector_type(4))) float float4v;
typedef __attribute__((ext_vector_type(4))) int i32x4;

static __device__ __forceinline__ unsigned short f2bf(float x) {
    unsigned int u = __float_as_uint(x);
    unsigned int r = (u + 0x7fffu + ((u >> 16) & 1u)) >> 16;
    return (unsigned short)r;
}
// packed f32 pair -> bf16x2 (compiler emits v_cvt_pk_bf16_f32)
static __device__ __forceinline__ uint32_t pk2bf(float lo, float hi) {
    union { __hip_bfloat162 v; uint32_t u; } c;
    c.v = __float22bfloat162_rn(float2{lo, hi});
    return c.u;
}

#define GLOAD16(gp, lp) __builtin_amdgcn_global_load_lds(                 \
    (const __attribute__((address_space(1))) void*)(gp),                  \
    (__attribute__((address_space(3))) void*)(lp), 16, 0, 0)
#define BAR() asm volatile("s_barrier" ::: "memory")
#define WAITV8() asm volatile("s_waitcnt vmcnt(8)" ::: "memory")
#define WAITV4() asm volatile("s_waitcnt vmcnt(4)" ::: "memory")
#define WAITV0() asm volatile("s_waitcnt vmcnt(0)" ::: "memory")

// ---- prep: z<4 -> transpose weight z (f32->bf16, Wt[n][k]);
//            z in 4..6 -> bulk f32->bf16 convert of xq/xk/xv ----
__global__ __launch_bounds__(256) void k_prep(const float* __restrict__ W0,
                                              const float* __restrict__ W1,
                                              const float* __restrict__ W2,
                                              const float* __restrict__ W3,
                                              unsigned short* __restrict__ Wt,
                                              const float* __restrict__ sq,
                                              const float* __restrict__ sk,
                                              const float* __restrict__ sv,
                                              unsigned short* __restrict__ Xb,
                                              int n8) {
    const int z = blockIdx.z;
    const int tx = threadIdx.x, ty = threadIdx.y;
    if (z < 4) {
        __shared__ unsigned short tile[32][33];
        const float* W = (z == 0) ? W0 : (z == 1) ? W1 : (z == 2) ? W2 : W3;
        unsigned short* dst = Wt + (size_t)z * DM * DM;
        int kb = blockIdx.x * 32, nb = blockIdx.y * 32;
#pragma unroll
        for (int i = 0; i < 4; ++i)
            tile[ty + i * 8][tx] = f2bf(W[(size_t)(kb + ty + i * 8) * DM + nb + tx]);
        __syncthreads();
#pragma unroll
        for (int i = 0; i < 4; ++i)
            dst[(size_t)(nb + ty + i * 8) * DM + kb + tx] = tile[tx][ty + i * 8];
    } else {
        const int c = z - 4;
        const float* s = (c == 0) ? sq : (c == 1) ? sk : sv;
        unsigned short* d = Xb + (size_t)c * n8 * 8;
        const int tid = ty * 32 + tx;
        int i = (blockIdx.y * 32 + blockIdx.x) * 256 + tid;
        const int stride = 32 * 32 * 256;
        for (; i < n8; i += stride) {
            const float4v* sp = (const float4v*)(s + (size_t)i * 8);
            float4v v0 = sp[0], v1 = sp[1];
            uint4 o;
            o.x = pk2bf(v0[0], v0[1]);
            o.y = pk2bf(v0[2], v0[3]);
            o.z = pk2bf(v1[0], v1[1]);
            o.w = pk2bf(v1[2], v1[3]);
            *(uint4*)(d + (size_t)i * 8) = o;
        }
    }
}

// ---- GEMM: C = A_bf16 @ W (+bias)*scale, BK=64, m97-style staging ----
// BATCHED==1: grid.z in {0,1,2}: z<2 scatter bf16 [b,h,t,d] into QKb;
// z==2 writes V^T [bh][d][t] directly (8B stores). BATCHED==0: f32 row-major.
template <int BATCHED>
__global__ __launch_bounds__(256) void k_gemm(const unsigned short* __restrict__ A0,
                                              const unsigned short* __restrict__ Bt0,
                                              const float* __restrict__ bias0,
                                              const float* __restrict__ bias1,
                                              const float* __restrict__ bias2,
                                              unsigned short* __restrict__ QKb,
                                              unsigned short* __restrict__ Vt,
                                              float* __restrict__ Cf,
                                              float scale0) {
    __shared__ __align__(16) char Asl[2][16384];
    __shared__ __align__(16) char Bsl[2][16384];
    const int tid = threadIdx.x;
    const int lane = tid & 63, wid = tid >> 6;
    const int lg = lane >> 4, lc = lane & 15;
    const int wm = wid >> 1, wn = wid & 1;
    const int m0 = blockIdx.x * 128, n0 = blockIdx.y * 128;
    const int z = BATCHED ? blockIdx.z : 0;

    const char* Ab = (const char*)(A0 + (size_t)z * NB * TT * DM);
    const char* Bb = (const char*)(Bt0 + (size_t)z * DM * DM);
    const float* bias = (z == 0) ? bias0 : (z == 1) ? bias1 : bias2;
    const float scale = (BATCHED && z != 0) ? 1.0f : scale0;

    f32x4 acc[4][4];
#pragma unroll
    for (int mi = 0; mi < 4; ++mi)
#pragma unroll
        for (int ni = 0; ni < 4; ++ni)
            acc[mi][ni] = (f32x4){0.f, 0.f, 0.f, 0.f};

    auto stage = [&](int buf, int k0) {
#pragma unroll
        for (int j = 0; j < 4; ++j) {
            const int row = j * 32 + (tid >> 3);
            const int swz = ((tid & 7) * 16) ^ ((row & 7) << 4);
            GLOAD16(Ab + (size_t)(m0 + row) * (DM * 2) + k0 * 2 + swz,
                    &Asl[buf][0] + j * 4096 + tid * 16);
            GLOAD16(Bb + (size_t)(n0 + row) * (DM * 2) + k0 * 2 + swz,
                    &Bsl[buf][0] + j * 4096 + tid * 16);
        }
    };

    stage(0, 0);
    __syncthreads();  // drains vmcnt(0) for the prologue tile

    int cur = 0;
    for (int t = 0; t < DM / 64; ++t) {
        if (t + 1 < DM / 64) {
            stage(cur ^ 1, (t + 1) * 64);
            WAITV8();  // current tile's 8 loads done; next tile's 8 in flight
        } else {
            WAITV0();
        }
        BAR();

#pragma unroll
        for (int kk = 0; kk < 2; ++kk) {
            bf16x8 af[4], bfr[4];
#pragma unroll
            for (int ni = 0; ni < 4; ++ni) {
                const int n = wn * 64 + ni * 16 + lc;
                bfr[ni] = *(const bf16x8*)(&Bsl[cur][0] + n * 128 +
                                           ((kk * 64 + lg * 16) ^ ((n & 7) << 4)));
            }
#pragma unroll
            for (int mi = 0; mi < 4; ++mi) {
                const int m = wm * 64 + mi * 16 + lc;
                af[mi] = *(const bf16x8*)(&Asl[cur][0] + m * 128 +
                                          ((kk * 64 + lg * 16) ^ ((m & 7) << 4)));
            }
            __builtin_amdgcn_s_setprio(1);
#pragma unroll
            for (int mi = 0; mi < 4; ++mi)
#pragma unroll
                for (int ni = 0; ni < 4; ++ni)
                    acc[mi][ni] = __builtin_amdgcn_mfma_f32_16x16x32_bf16(af[mi], bfr[ni],
                                                                          acc[mi][ni], 0, 0, 0);
            __builtin_amdgcn_s_setprio(0);
        }
        BAR();
        cur ^= 1;
    }

#pragma unroll
    for (int mi = 0; mi < 4; ++mi)
#pragma unroll
        for (int ni = 0; ni < 4; ++ni) {
            const int m = m0 + wm * 64 + mi * 16 + lg * 4;
            const int n = n0 + wn * 64 + ni * 16 + lc;
            float v[4];
#pragma unroll
            for (int r = 0; r < 4; ++r) v[r] = (acc[mi][ni][r] + bias[n]) * scale;
            if (!BATCHED) {
#pragma unroll
                for (int r = 0; r < 4; ++r) Cf[(size_t)(m + r) * DM + n] = v[r];
            } else {
                const int b = m >> 11, tl = m & (TT - 1), h = n >> 6, d = n & 63;
                if (z == 2) {
                    // V^T [bh][d][t]: 4 consecutive t, same d -> one 8B store
                    uint2 w;
                    w.x = pk2bf(v[0], v[1]);
                    w.y = pk2bf(v[2], v[3]);
                    *(uint2*)(Vt + ((size_t)(b * NH + h) * HD + d) * TT + tl) = w;
                } else {
#pragma unroll
                    for (int r = 0; r < 4; ++r)
                        QKb[(size_t)z * NB * NH * TT * HD +
                            (((size_t)b * NH + h) * TT + tl + r) * HD + d] = f2bf(v[r]);
                }
            }
        }
}

// ---- flash attention, swapped-QK^T 32x32 MFMA, in-register softmax ----
// 8 waves x 32 q-rows (QBLK=256). KV staged in 128-key tiles; compute in two
// 64-key halves reusing registers. LDS fragment order (conflict-free reads).
// Softmax in round-14 (measured-best) linear form.
// Grid 512, 1-D; blocks i and i+256 share a CU: complementary causal halves,
// same head (L2 reuse). S^T = mfma(K,Q): col=lane&31=q,
// reg r holds key (r&3)+8*(r>>2)+4*(lane>>5).
__global__ __launch_bounds__(512) void k_attn(const unsigned short* __restrict__ Qg,
                                              const unsigned short* __restrict__ Kg,
                                              const unsigned short* __restrict__ Vtg,
                                              const int* __restrict__ pm,
                                              unsigned short* __restrict__ Og) {
    __shared__ __align__(16) unsigned short Kl[2][KVB * HD];  // 16 KB per buf
    __shared__ __align__(16) unsigned short Vl[2][KVB * HD];  // V^T tile, frag order
    __shared__ uint64_t pmbits[TT / 64];

    const int idx = blockIdx.x;
    const int half = idx >> 8, r5 = idx & 255;
    const int a = r5 & 3;
    const int qb = half ? (7 - a) : a;
    const int bh = r5 >> 2;
    const int b = bh >> 4, h = bh & 15;
    const int qbase = qb * QBLK;
    const int tid = threadIdx.x;
    const int wid = tid >> 6, lane = tid & 63;
    const int hi = lane >> 5, l31 = lane & 31;
    const int q0 = qbase + wid * 32;
    const int q = q0 + l31;

    const unsigned short* Qh = Qg + (size_t)bh * TT * HD;
    const char* Khb = (const char*)(Kg + (size_t)bh * TT * HD);
    const char* Vthb = (const char*)(Vtg + (size_t)bh * HD * TT);
    const int* pmb = pm + b * TT;

    char* const kdst = (char*)&Kl[0][0];
    char* const vdst = (char*)&Vl[0][0];

    // stage one 128-key tile: 4 GLOAD16/thread (K: 2 key-halves x chunk wid;
    // V: 2 chunk-halves x d=lane). Buffer stride 16384 B.
#define ASTAGE(buf, kv0_)                                                        \
    {                                                                            \
        _Pragma("unroll")                                                        \
        for (int p = 0; p < 2; ++p) {                                            \
            GLOAD16(Khb + (size_t)((kv0_) + p * 64 + lane) * 128 + wid * 16,     \
                    kdst + (buf) * 16384 + wid * 2048 + p * 1024 + lane * 16);   \
            GLOAD16(Vthb + (size_t)lane * 4096 + (size_t)(kv0_) * 2 + (p * 8 + wid) * 16, \
                    vdst + (buf) * 16384 + p * 8192 + wid * 1024 + lane * 16);   \
        }                                                                        \
    }

    // prologue: stage tile 0 (drained by the __syncthreads below)
    ASTAGE(0, 0);

    // padding-mask bitmasks (one u64 per 64-key group); bit=1 -> key valid
#pragma unroll
    for (int it = 0; it < 4; ++it) {
        const int g = wid + it * 8;
        unsigned long long msk = __ballot(pmb[g * 64 + lane] != 0);
        if (lane == 0) pmbits[g] = msk;
    }

    // hoist Q fragments (B-operand: col q = lane&31, d-chunk dd*16 + hi*8)
    bf16x8 qf[4];
#pragma unroll
    for (int dd = 0; dd < 4; ++dd)
        qf[dd] = *(const bf16x8*)((const char*)Qh + (size_t)q * 128 + dd * 32 + hi * 16);

    f32x16 o0, o1;
#pragma unroll
    for (int r = 0; r < 16; ++r) { o0[r] = 0.f; o1[r] = 0.f; }
    float mrow = -INFINITY, msafe = -1.0e30f, lrow = 0.f;

    __syncthreads();  // pmbits visible; tile-0 loads drained (vmcnt 0)

    const int nt = (qbase + QBLK) >> 7;  // 2*(qb+1) 128-key tiles
    int cur = 0;
    for (int t = 0; t < nt; ++t) {
        const int kv0 = t << 7;
        if (t + 1 < nt) {
            ASTAGE(cur ^ 1, kv0 + KVB);
            WAITV4();  // current tile's 4 loads done; next tile's 4 in flight
        } else {
            WAITV0();
        }
        BAR();

        const char* kb = (const char*)&Kl[0][0] + cur * 16384;
        const char* vbp = (const char*)&Vl[0][0] + cur * 16384;

#pragma unroll
        for (int hh = 0; hh < 2; ++hh) {
            const int k0 = kv0 + hh * 64;
            if (k0 > q0 + 31) continue;  // wave-uniform causal skip

            const uint64_t vb = pmbits[k0 >> 6];
            const uint32_t pm0 = ((uint32_t)vb) >> (4 * hi);
            const uint32_t pm1 = ((uint32_t)(vb >> 32)) >> (4 * hi);
            const bool allvalid = (vb == ~0ull);
            const bool do2 = (k0 + 32 <= q0 + 31);
            const bool needmask = (k0 + 63 > q0) || !allvalid;
            const char* kbh = kb + hh * 1024;     // +64-key half within chunk
            const char* vbh = vbp + hh * 8192;    // +8 chunks for key half

            // ---- QK^T: S^T[key][q] ----
            f32x16 st0, st1;
#pragma unroll
            for (int r = 0; r < 16; ++r) { st0[r] = 0.f; st1[r] = 0.f; }
            __builtin_amdgcn_s_setprio(1);
#pragma unroll
            for (int dd = 0; dd < 4; ++dd) {
                const char* kchunk = kbh + (dd * 2 + hi) * 2048;
                bf16x8 kf = *(const bf16x8*)(kchunk + l31 * 16);
                st0 = __builtin_amdgcn_mfma_f32_32x32x16_bf16(kf, qf[dd], st0, 0, 0, 0);
            }
            if (do2) {
#pragma unroll
                for (int dd = 0; dd < 4; ++dd) {
                    const char* kchunk = kbh + (dd * 2 + hi) * 2048;
                    bf16x8 kf = *(const bf16x8*)(kchunk + 512 + l31 * 16);
                    st1 = __builtin_amdgcn_mfma_f32_32x32x16_bf16(kf, qf[dd], st1, 0, 0, 0);
                }
            }
            __builtin_amdgcn_s_setprio(0);

            // ---- masking (causal + padding), lane-local ----
            const int qr = q - k0 - 4 * hi;
            if (needmask) {
#pragma unroll
                for (int r = 0; r < 16; ++r) {
                    const int c = (r & 3) + 8 * (r >> 2);
                    st0[r] = (((pm0 >> c) & 1) && (c <= qr)) ? st0[r] : -INFINITY;
                }
                if (do2) {
#pragma unroll
                    for (int r = 0; r < 16; ++r) {
                        const int c = (r & 3) + 8 * (r >> 2);
                        st1[r] = (((pm1 >> c) & 1) && (c + 32 <= qr)) ? st1[r] : -INFINITY;
                    }
                }
            }

            // ---- online softmax, in-register, defer-max (T13) ----
            float mloc = -INFINITY;
#pragma unroll
            for (int r = 0; r < 16; ++r) mloc = fmaxf(mloc, st0[r]);
            if (do2) {
#pragma unroll
                for (int r = 0; r < 16; ++r) mloc = fmaxf(mloc, st1[r]);
            }
            const float cmax = fmaxf(mloc, __shfl_xor(mloc, 32, 64));
            // rescale only when max moved >8 (exp2 domain); invariant
            // msafe == max(mrow, -1e30) holds (deferral updates neither).
            if (!__all(cmax - mrow <= 8.0f)) {
                const float mnew = fmaxf(mrow, cmax);
                const float ms = fmaxf(mnew, -1.0e30f);
                const float esc = __builtin_amdgcn_exp2f(mrow - ms);  // -inf -> 0
#pragma unroll
                for (int r = 0; r < 16; ++r) { o0[r] *= esc; o1[r] *= esc; }
                lrow *= esc;
                mrow = mnew;
                msafe = ms;
            }

            // exponentials vs finite msafe (masked -inf -> 0; bounded by 2^8)
            float tot = 0.f;
#pragma unroll
            for (int r = 0; r < 16; ++r) {
                st0[r] = __builtin_amdgcn_exp2f(st0[r] - msafe);
                tot += st0[r];
            }
            if (do2) {
#pragma unroll
                for (int r = 0; r < 16; ++r) {
                    st1[r] = __builtin_amdgcn_exp2f(st1[r] - msafe);
                    tot += st1[r];
                }
            }
            lrow += tot + __shfl_xor(tot, 32, 64);

            // ---- P -> bf16 B-fragments (pair redistribution via shfl) + PV ----
            __builtin_amdgcn_s_setprio(1);
#pragma unroll
            for (int kc = 0; kc < 2; ++kc) {
                uint32_t A0 = pk2bf(st0[kc * 8 + 0], st0[kc * 8 + 1]);
                uint32_t A1 = pk2bf(st0[kc * 8 + 2], st0[kc * 8 + 3]);
                uint32_t C0 = pk2bf(st0[kc * 8 + 4], st0[kc * 8 + 5]);
                uint32_t C1 = pk2bf(st0[kc * 8 + 6], st0[kc * 8 + 7]);
                uint32_t oA0 = __shfl_xor(A0, 32, 64), oA1 = __shfl_xor(A1, 32, 64);
                uint32_t oC0 = __shfl_xor(C0, 32, 64), oC1 = __shfl_xor(C1, 32, 64);
                i32x4 pf = {(int)(hi ? oC0 : A0), (int)(hi ? oC1 : A1),
                            (int)(hi ? C0 : oA0), (int)(hi ? C1 : oA1)};
                bf16x8 pb = *(bf16x8*)&pf;
                const char* vchunk = vbh + (kc * 2 + hi) * 1024;
                {
                    bf16x8 vf = *(const bf16x8*)(vchunk + l31 * 16);
                    o0 = __builtin_amdgcn_mfma_f32_32x32x16_bf16(vf, pb, o0, 0, 0, 0);
                }
                {
                    bf16x8 vf = *(const bf16x8*)(vchunk + 512 + l31 * 16);
                    o1 = __builtin_amdgcn_mfma_f32_32x32x16_bf16(vf, pb, o1, 0, 0, 0);
                }
            }
            if (do2) {
#pragma unroll
                for (int kc = 0; kc < 2; ++kc) {
                    uint32_t A0 = pk2bf(st1[kc * 8 + 0], st1[kc * 8 + 1]);
                    uint32_t A1 = pk2bf(st1[kc * 8 + 2], st1[kc * 8 + 3]);
                    uint32_t C0 = pk2bf(st1[kc * 8 + 4], st1[kc * 8 + 5]);
                    uint32_t C1 = pk2bf(st1[kc * 8 + 6], st1[kc * 8 + 7]);
                    uint32_t oA0 = __shfl_xor(A0, 32, 64), oA1 = __shfl_xor(A1, 32, 64);
                    uint32_t oC0 = __shfl_xor(C0, 32, 64), oC1 = __shfl_xor(C1, 32, 64);
                    i32x4 pf = {(int)(hi ? oC0 : A0), (int)(hi ? oC1 : A1),
                                (int)(hi ? C0 : oA0), (int)(hi ? C1 : oA1)};
                    bf16x8 pb = *(bf16x8*)&pf;
                    const char* vchunk = vbh + (4 + kc * 2 + hi) * 1024;
                    {
                        bf16x8 vf = *(const bf16x8*)(vchunk + l31 * 16);
                        o0 = __builtin_amdgcn_mfma_f32_32x32x16_bf16(vf, pb, o0, 0, 0, 0);
                    }
                    {
                        bf16x8 vf = *(const bf16x8*)(vchunk + 512 + l31 * 16);
                        o1 = __builtin_amdgcn_mfma_f32_32x32x16_bf16(vf, pb, o1, 0, 0, 0);
                    }
                }
            }
            __builtin_amdgcn_s_setprio(0);
        }
        BAR();
        cur ^= 1;
    }

    // ---- epilogue: normalize, write bf16 [b*T+q][h*64+d], 8B packed stores ----
    const float inv = (lrow > 0.f) ? (1.0f / lrow) : 0.f;
    unsigned short* orow = Og + ((size_t)(b * TT + q)) * DM + h * HD;
#pragma unroll
    for (int g4 = 0; g4 < 4; ++g4) {
        uint32_t w0 = pk2bf(o0[g4 * 4 + 0] * inv, o0[g4 * 4 + 1] * inv);
        uint32_t w1 = pk2bf(o0[g4 * 4 + 2] * inv, o0[g4 * 4 + 3] * inv);
        *(uint2*)(orow + g4 * 8 + 4 * hi) = make_uint2(w0, w1);
    }
#pragma unroll
    for (int g4 = 0; g4 < 4; ++g4) {
        uint32_t w0 = pk2bf(o1[g4 * 4 + 0] * inv, o1[g4 * 4 + 1] * inv);
        uint32_t w1 = pk2bf(o1[g4 * 4 + 2] * inv, o1[g4 * 4 + 3] * inv);
        *(uint2*)(orow + 32 + g4 * 8 + 4 * hi) = make_uint2(w0, w1);
    }
}

extern "C" void kernel_launch(void* const* d_in, const int* in_sizes, int n_in,
                              void* d_out, int out_size, void* d_ws, size_t ws_size,
                              hipStream_t stream) {
    const float* xq = (const float*)d_in[0];
    const float* xk = (const float*)d_in[1];
    const float* xv = (const float*)d_in[2];
    const int* pmask = (const int*)d_in[3];
    const float* Wq = (const float*)d_in[4];
    const float* bq = (const float*)d_in[5];
    const float* Wk = (const float*)d_in[6];
    const float* bk = (const float*)d_in[7];
    const float* Wv = (const float*)d_in[8];
    const float* bv = (const float*)d_in[9];
    const float* Wo = (const float*)d_in[10];
    const float* bo = (const float*)d_in[11];

    char* ws = (char*)d_ws;
    const size_t WT = (size_t)DM * DM * 2;             // 2 MB per transposed weight
    const size_t QKV = (size_t)NB * NH * TT * HD * 2;  // 16 MB each
    unsigned short* WqT = (unsigned short*)(ws + 0 * WT);   // Wq/Wk/Wv/Wo^T contiguous
    unsigned short* WoT = WqT + 3 * (size_t)DM * DM;
    unsigned short* Qb = (unsigned short*)(ws + 4 * WT);    // Qb, Kb contiguous
    unsigned short* Kb = (unsigned short*)(ws + 4 * WT + QKV);
    unsigned short* Vt = (unsigned short*)(ws + 4 * WT + 2 * QKV);
    unsigned short* Ob = (unsigned short*)(ws + 4 * WT + 3 * QKV);
    unsigned short* Xb = (unsigned short*)(ws + 4 * WT + 4 * QKV);  // Xq/Xk/Xv 48 MB

    const float qscale = 0.125f * 1.44269504088896340736f;  // 1/sqrt(64) * log2(e)
    const int n8 = NB * TT * DM / 8;

    k_prep<<<dim3(32, 32, 7), dim3(32, 8), 0, stream>>>(Wq, Wk, Wv, Wo, WqT,
                                                        xq, xk, xv, Xb, n8);
    k_gemm<1><<<dim3(64, 8, 3), 256, 0, stream>>>(Xb, WqT, bq, bk, bv,
                                                  Qb, Vt, nullptr, qscale);

    k_attn<<<dim3((TT / QBLK) * NB * NH), 512, 0, stream>>>(Qb, Kb, Vt, pmask, Ob);

    k_gemm<0><<<dim3(64, 8, 1), 256, 0, stream>>>(Ob, WoT, bo, bo, bo,
                                                  nullptr, nullptr, (float*)d_out, 1.0f);
}